// Round 2
// baseline (89.352 us; speedup 1.0000x reference)
//
#include <hip/hip_runtime.h>

typedef __bf16 bf16x8 __attribute__((ext_vector_type(8)));
typedef float f32x4 __attribute__((ext_vector_type(4)));
typedef unsigned short ushort8 __attribute__((ext_vector_type(8)));
typedef unsigned short ushort4v __attribute__((ext_vector_type(4)));

#define S_LEN 2048
#define DMODEL 1024
#define DHEAD 64
#define QK_SCALE 0.18033688f  /* (1/8) * log2(e) */

static __device__ __forceinline__ unsigned short f2bf(float x) {
  __bf16 h = (__bf16)x;
  return __builtin_bit_cast(unsigned short, h);
}

static __device__ __forceinline__ f32x4 mfma16(bf16x8 a, bf16x8 b, f32x4 c) {
  return __builtin_amdgcn_mfma_f32_16x16x32_bf16(a, b, c, 0, 0, 0);
}

static __device__ __forceinline__ bf16x8 u2bf(ushort8 u) {
  return __builtin_bit_cast(bf16x8, u);
}

// ---- fused prep: wiT [64][1024] bf16  +  wosumT [1024][64] bf16
// wosumT[j][d] = sum_h Wo[h*64+d][j]  (tile(head,16)@Wo == head@Wo_sum; B-frag layout)
__global__ void prep_kernel(const float* __restrict__ wi, const float* __restrict__ Wo,
                            unsigned short* __restrict__ wiT,
                            unsigned short* __restrict__ wosumT) {
  int i = blockIdx.x * 256 + threadIdx.x;  // 131072 total
  if (i < 65536) {
    int n = i >> 10, kk = i & 1023;
    wiT[i] = f2bf(wi[(size_t)kk * DHEAD + n]);
  } else {
    int idx = i - 65536;
    int j = idx & 1023, d = idx >> 10;  // consecutive lanes -> consecutive j (coalesced)
    float s = 0.f;
#pragma unroll
    for (int h = 0; h < 16; ++h) s += Wo[(size_t)(h * 64 + d) * 1024 + j];
    wosumT[(size_t)j * 64 + d] = f2bf(s);
  }
}

// ---- projections: LDS-free, barrier-free register GEMM, depth-4 prefetch.
// r1 post-mortem: compiler allocated only 48 VGPRs (occupancy-targeted default for a
// 64-thread block) -> both Stage buffers could not stay live -> loads sank to their
// uses -> 32 serialized memory round-trips/wave (41us, HBM 17%). Grid gives only
// 6 waves/CU (1.5/EU), so that register thrift bought nothing. Fix: declare
// waves_per_eu(1,2) to unlock the VGPR file, and 4 NAMED stages (static indexing,
// rule #20) with unconditional loads in a 7-iter steady-state loop + load-free tail.
struct Stage {
  f32x4 a0, a1;            // 8 fp32 of this lane's A-row chunk (row=l15, k=lg*8..+8)
  ushort8 b0, b1, b2, b3;  // B-frags for the 4 n-subtiles (n=t*16+l15, k=lg*8..+8)
};

static __device__ __forceinline__ void stage_load(Stage& s, const float* __restrict__ arow,
                                                  const unsigned short* __restrict__ brow,
                                                  int kt) {
  const float* ap = arow + kt * 32;
  s.a0 = *(const f32x4*)ap;
  s.a1 = *(const f32x4*)(ap + 4);
  const unsigned short* bp = brow + kt * 32;
  s.b0 = *(const ushort8*)bp;
  s.b1 = *(const ushort8*)(bp + 16 * 1024);
  s.b2 = *(const ushort8*)(bp + 32 * 1024);
  s.b3 = *(const ushort8*)(bp + 48 * 1024);
}

static __device__ __forceinline__ void stage_comp(const Stage& s, f32x4* acc) {
  bf16x8 af;
  af[0] = (__bf16)s.a0[0]; af[1] = (__bf16)s.a0[1];
  af[2] = (__bf16)s.a0[2]; af[3] = (__bf16)s.a0[3];
  af[4] = (__bf16)s.a1[0]; af[5] = (__bf16)s.a1[1];
  af[6] = (__bf16)s.a1[2]; af[7] = (__bf16)s.a1[3];
  acc[0] = mfma16(af, u2bf(s.b0), acc[0]);
  acc[1] = mfma16(af, u2bf(s.b1), acc[1]);
  acc[2] = mfma16(af, u2bf(s.b2), acc[2]);
  acc[3] = mfma16(af, u2bf(s.b3), acc[3]);
}

__global__ __launch_bounds__(64)
__attribute__((amdgpu_waves_per_eu(1, 2)))
void proj_kernel(
    const float* __restrict__ q, const float* __restrict__ k, const float* __restrict__ v,
    const unsigned short* __restrict__ wiT,
    float* __restrict__ qp32, unsigned short* __restrict__ qp_bf,
    unsigned short* __restrict__ kp_bf, unsigned short* __restrict__ vpT) {
  int bx = blockIdx.x;       // 1536 blocks: 512 per tensor
  int ten = bx >> 9;         // 0:q 1:k 2:v
  int m0 = (bx & 511) << 4;  // 16-row strip
  const float* x = (ten == 0) ? q : ((ten == 1) ? k : v);
  int lane = threadIdx.x;
  int l15 = lane & 15, lg = lane >> 4;

  const float* arow = x + (size_t)(m0 + l15) * DMODEL + lg * 8;
  const unsigned short* brow = wiT + (size_t)l15 * DMODEL + lg * 8;

  Stage s0, s1, s2, s3;  // named stages: all accesses compile-time constant
  stage_load(s0, arow, brow, 0);
  stage_load(s1, arow, brow, 1);
  stage_load(s2, arow, brow, 2);
  stage_load(s3, arow, brow, 3);

  f32x4 acc[4] = {};
#pragma unroll 1
  for (int kt = 0; kt < 28; kt += 4) {  // steady state: loads unconditional
    stage_comp(s0, acc);
    stage_load(s0, arow, brow, kt + 4);
    stage_comp(s1, acc);
    stage_load(s1, arow, brow, kt + 5);
    stage_comp(s2, acc);
    stage_load(s2, arow, brow, kt + 6);
    stage_comp(s3, acc);
    stage_load(s3, arow, brow, kt + 7);
  }
  // tail: stages 28..31, no further loads
  stage_comp(s0, acc);
  stage_comp(s1, acc);
  stage_comp(s2, acc);
  stage_comp(s3, acc);

  if (ten == 2) {
    // transpose 16 kv-rows x 64 d through tiny LDS, store vpT [b][dh][kv]
    __shared__ __align__(16) unsigned short vt[16][72];
#pragma unroll
    for (int t = 0; t < 4; ++t)
#pragma unroll
      for (int r = 0; r < 4; ++r)
        vt[lg * 4 + r][t * 16 + l15] = f2bf(acc[t][r]);
    __syncthreads();  // single-wave block: cheap
    int bq = m0 >> 11, kvb = m0 & 2047;
    unsigned short* dst = vpT + (size_t)bq * (DHEAD * S_LEN) + (size_t)lane * S_LEN + kvb;
    ushort8 o0, o1;
#pragma unroll
    for (int j = 0; j < 8; ++j) {
      o0[j] = vt[j][lane];
      o1[j] = vt[8 + j][lane];
    }
    *(ushort8*)dst = o0;
    *(ushort8*)(dst + 8) = o1;
  } else {
#pragma unroll
    for (int t = 0; t < 4; ++t) {
      int gc = t * 16 + l15;
#pragma unroll
      for (int r = 0; r < 4; ++r) {
        size_t idx = (size_t)(m0 + lg * 4 + r) * DHEAD + gc;
        float val = acc[t][r];
        if (ten == 0) {
          qp32[idx] = val;
          qp_bf[idx] = f2bf(val * QK_SCALE);
        } else {
          kp_bf[idx] = f2bf(val);
        }
      }
    }
  }
}

// ---- flash attention, fixed-max softmax, 4-way KV split per block
// NO in-loop barriers: P_lds[w] is written AND read by wave w only -- the
// compiler's lgkmcnt dependency wait orders the round-trip. Waves fully
// decoupled until the final cross-wave combine barrier.
__global__ __launch_bounds__(256) void attn_kernel(
    const unsigned short* __restrict__ qp_bf, const unsigned short* __restrict__ kp_bf,
    const unsigned short* __restrict__ vpT, const float* __restrict__ qp32,
    unsigned short* __restrict__ head_bf) {
  int bx = blockIdx.x;
  int b = bx >> 7;
  int q0 = (bx & 127) << 4;
  int tid = threadIdx.x, lane = tid & 63, w = tid >> 6;
  int l15 = lane & 15, lg = lane >> 4;

  __shared__ __align__(16) unsigned short P_lds[4][16][72];  // per-wave P round-trip
  __shared__ __align__(16) float part[4][16][64];            // per-wave PV partials
  __shared__ float lsum_lds[4][16];                          // per-wave denom partials

  size_t base = (size_t)b * (S_LEN * DHEAD);
  const unsigned short* qrow_p = qp_bf + base + (size_t)(q0 + l15) * DHEAD + lg * 8;
  bf16x8 qf0 = *(const bf16x8*)qrow_p;  // B-frag: n=q, k=dh
  bf16x8 qf1 = *(const bf16x8*)(qrow_p + 32);

  const unsigned short* vbase = vpT + (size_t)b * (DHEAD * S_LEN);

  f32x4 oacc[4] = {};
  float lsum_p = 0.f;  // per-lane partial denom for q = q0 + l15

  for (int it = 0; it < 8; ++it) {
    int kv0 = w * 512 + it * 64;
    const unsigned short* kt = kp_bf + base + (size_t)kv0 * DHEAD;
    f32x4 sc[4];
    // swapped QK^T: mfma(K,Q) -> lane holds S(q = q0+l15, kv = kv0 + sub*16 + lg*4 + r)
#pragma unroll
    for (int sub = 0; sub < 4; ++sub) {
      bf16x8 kf0 = *(const bf16x8*)(kt + (size_t)(sub * 16 + l15) * DHEAD + lg * 8);
      bf16x8 kf1 = *(const bf16x8*)(kt + (size_t)(sub * 16 + l15) * DHEAD + 32 + lg * 8);
      f32x4 z = {};
      z = mfma16(kf0, qf0, z);
      sc[sub] = mfma16(kf1, qf1, z);
    }
    // fixed-max softmax: p = exp2(s); denom deferred (per-lane partial, q is lane-local)
#pragma unroll
    for (int sub = 0; sub < 4; ++sub) {
      ushort4v pw;
#pragma unroll
      for (int r = 0; r < 4; ++r) {
        float p = exp2f(sc[sub][r]);
        lsum_p += p;
        pw[r] = f2bf(p);
      }
      *(ushort4v*)&P_lds[w][l15][sub * 16 + lg * 4] = pw;  // row-local packed b64 write
    }
    // PV: A-frag = P (m=q, k=kv), B-frag = V^T (n=dh, k=kv), same k-order both sides
#pragma unroll
    for (int c = 0; c < 2; ++c) {
      bf16x8 pf = *(const bf16x8*)&P_lds[w][l15][c * 32 + lg * 8];  // same-wave read
      const unsigned short* vt = vbase + kv0 + c * 32 + lg * 8;
#pragma unroll
      for (int t = 0; t < 4; ++t) {
        bf16x8 vf = *(const bf16x8*)(vt + (size_t)(t * 16 + l15) * S_LEN);
        oacc[t] = mfma16(pf, vf, oacc[t]);
      }
    }
  }

  // finish denom: reduce across the 4 lg groups (same l15 = same q)
  lsum_p += __shfl_xor(lsum_p, 16);
  lsum_p += __shfl_xor(lsum_p, 32);

  // write per-wave partials (fixed-max => partials combine by plain addition)
#pragma unroll
  for (int t = 0; t < 4; ++t)
#pragma unroll
    for (int r = 0; r < 4; ++r)
      part[w][lg * 4 + r][t * 16 + l15] = oacc[t][r];
  if (lane < 16) lsum_lds[w][l15] = lsum_p;
  __syncthreads();  // cross-wave combine barrier (stays)

  {
    int qr = tid >> 4, d0 = (tid & 15) << 2;
    f32x4 s = *(const f32x4*)&part[0][qr][d0];
    s += *(const f32x4*)&part[1][qr][d0];
    s += *(const f32x4*)&part[2][qr][d0];
    s += *(const f32x4*)&part[3][qr][d0];
    float l = lsum_lds[0][qr] + lsum_lds[1][qr] + lsum_lds[2][qr] + lsum_lds[3][qr];
    float inv = 1.0f / l;
    size_t idx = base + (size_t)(q0 + qr) * DHEAD + d0;
    f32x4 qv = *(const f32x4*)(qp32 + idx);
    f32x4 res = qv + s * inv;
    ushort4v hb;
#pragma unroll
    for (int j = 0; j < 4; ++j) hb[j] = f2bf(res[j]);
    *(ushort4v*)(head_bf + idx) = hb;  // bf16 head: residual + normalized PV
  }
}

// ---- out = head_bf[8192x64] @ wosumT^T [64x1024] + bo, via MFMA (K=64)
// Same fragment conventions as proj (A rows = m, B rows = n, verified C-layout).
__global__ __launch_bounds__(256) void out_kernel(
    const unsigned short* __restrict__ head_bf, const unsigned short* __restrict__ wosumT,
    const float* __restrict__ bo, float* __restrict__ out) {
  int bx = blockIdx.x;
  int m0 = (bx >> 3) << 6;  // 128 row-blocks of 64
  int c0 = (bx & 7) << 7;   // 8 col-blocks of 128
  int tid = threadIdx.x, lane = tid & 63, w = tid >> 6;
  int l15 = lane & 15, lg = lane >> 4;

  const unsigned short* ap = head_bf + (size_t)(m0 + w * 16 + l15) * DHEAD + lg * 8;
  bf16x8 af0 = *(const bf16x8*)ap;         // k = lg*8..+8
  bf16x8 af1 = *(const bf16x8*)(ap + 32);  // k = 32+lg*8..+8

  f32x4 acc[8] = {};
#pragma unroll
  for (int t = 0; t < 8; ++t) {
    const unsigned short* bp = wosumT + (size_t)(c0 + t * 16 + l15) * DHEAD + lg * 8;
    bf16x8 b0 = *(const bf16x8*)bp;
    bf16x8 b1 = *(const bf16x8*)(bp + 32);
    acc[t] = mfma16(af0, b0, acc[t]);
    acc[t] = mfma16(af1, b1, acc[t]);
  }
#pragma unroll
  for (int t = 0; t < 8; ++t) {
    int col = c0 + t * 16 + l15;
    float bias = bo[col];
#pragma unroll
    for (int r = 0; r < 4; ++r) {
      int row = m0 + w * 16 + lg * 4 + r;
      out[(size_t)row * 1024 + col] = acc[t][r] + bias;
    }
  }
}

extern "C" void kernel_launch(void* const* d_in, const int* in_sizes, int n_in,
                              void* d_out, int out_size, void* d_ws, size_t ws_size,
                              hipStream_t stream) {
  (void)in_sizes; (void)n_in; (void)out_size; (void)ws_size;
  const float* v = (const float*)d_in[0];
  const float* k = (const float*)d_in[1];
  const float* q = (const float*)d_in[2];
  const float* wi = (const float*)d_in[3];
  const float* Wo = (const float*)d_in[4];
  const float* bo = (const float*)d_in[5];
  float* out = (float*)d_out;
  char* ws = (char*)d_ws;

  float* qp32 = (float*)(ws + 0);                                // 2 MB
  unsigned short* head_bf = (unsigned short*)(ws + (2u << 20));  // 1 MB
  unsigned short* qp_bf = (unsigned short*)(ws + (4u << 20));    // 1 MB
  unsigned short* kp_bf = (unsigned short*)(ws + (5u << 20));    // 1 MB
  unsigned short* vpT = (unsigned short*)(ws + (6u << 20));      // 1 MB  [b][dh][kv]
  unsigned short* wiT = (unsigned short*)(ws + (7u << 20));      // 128 KB
  unsigned short* wosumT = (unsigned short*)(ws + (7u << 20) + (512u << 10));  // 128 KB

  prep_kernel<<<512, 256, 0, stream>>>(wi, Wo, wiT, wosumT);
  proj_kernel<<<1536, 64, 0, stream>>>(q, k, v, wiT, qp32, qp_bf, kp_bf, vpT);
  attn_kernel<<<512, 256, 0, stream>>>(qp_bf, kp_bf, vpT, qp32, head_bf);
  out_kernel<<<1024, 256, 0, stream>>>(head_bf, wosumT, bo, out);
}

// Round 3
// 75.161 us; speedup vs baseline: 1.1888x; 1.1888x over previous
//
#include <hip/hip_runtime.h>

typedef __bf16 bf16x8 __attribute__((ext_vector_type(8)));
typedef float f32x4 __attribute__((ext_vector_type(4)));
typedef unsigned short ushort8 __attribute__((ext_vector_type(8)));
typedef unsigned short ushort4v __attribute__((ext_vector_type(4)));

#define S_LEN 2048
#define DMODEL 1024
#define DHEAD 64
#define QK_SCALE 0.18033688f  /* (1/8) * log2(e) */

static __device__ __forceinline__ unsigned short f2bf(float x) {
  __bf16 h = (__bf16)x;
  return __builtin_bit_cast(unsigned short, h);
}

static __device__ __forceinline__ f32x4 mfma16(bf16x8 a, bf16x8 b, f32x4 c) {
  return __builtin_amdgcn_mfma_f32_16x16x32_bf16(a, b, c, 0, 0, 0);
}

#define GLOAD_LDS(SRC, DST)                                                            \
  __builtin_amdgcn_global_load_lds(                                                    \
      (const __attribute__((address_space(1))) void*)(SRC),                            \
      (__attribute__((address_space(3))) void*)(DST), 16, 0, 0)

// ---- fused prep: wiT [64][1024] bf16  +  wosumT [1024][64] bf16
// wosumT[j][d] = sum_h Wo[h*64+d][j]  (tile(head,16)@Wo == head@Wo_sum; B-frag layout)
__global__ void prep_kernel(const float* __restrict__ wi, const float* __restrict__ Wo,
                            unsigned short* __restrict__ wiT,
                            unsigned short* __restrict__ wosumT) {
  int i = blockIdx.x * 256 + threadIdx.x;  // 131072 total
  if (i < 65536) {
    int n = i >> 10, kk = i & 1023;
    wiT[i] = f2bf(wi[(size_t)kk * DHEAD + n]);
  } else {
    int idx = i - 65536;
    int j = idx & 1023, d = idx >> 10;  // consecutive lanes -> consecutive j (coalesced)
    float s = 0.f;
#pragma unroll
    for (int h = 0; h < 16; ++h) s += Wo[(size_t)(h * 64 + d) * 1024 + j];
    wosumT[(size_t)j * 64 + d] = f2bf(s);
  }
}

// ---- projections: single-wave blocks, LDS DMA ring, counted vmcnt pipeline.
// r1/r2 post-mortem: register-resident prefetch is un-compilable (scheduler sinks
// loads / RA spills; 43us independent of HBM-vs-L3 tier => pure latency chain).
// Fix: in-flight data lives in the vmcnt queue + LDS ring, not VGPRs.
//   - 1 wave/block, 16 output rows; 32 K-stages of 32 cols.
//   - per stage: 2 A-DMAs (16 rows x 128B, fp32) + 4 B-DMAs (64 n-rows x 64B, bf16)
//     via global_load_lds (dest linear; XOR-swizzle folded into per-lane SOURCE addr).
//   - DEPTH=4 ring, 3 stages (18 DMAs) in flight; s_waitcnt vmcnt(18) per stage
//     (never 0 in-loop), sched_barrier(0) fences per rule #18.
//   - LDS 26.9KB => 6 blocks/CU = entire 1536-block grid resident.
// In-flight/CU = 6 waves * 18KB = 108KB >> BW*latency (~9KB) => HBM-BW-bound (~15us).
__global__ __launch_bounds__(64) void proj_kernel(
    const float* __restrict__ q, const float* __restrict__ k, const float* __restrict__ v,
    const unsigned short* __restrict__ wiT,
    float* __restrict__ qp32, unsigned short* __restrict__ qp_bf,
    unsigned short* __restrict__ kp_bf, unsigned short* __restrict__ vpT) {
  int bx = blockIdx.x;       // 1536 blocks: 512 per tensor
  int ten = bx >> 9;         // 0:q 1:k 2:v
  int m0 = (bx & 511) << 4;  // 16-row strip
  const float* x = (ten == 0) ? q : ((ten == 1) ? k : v);
  int lane = threadIdx.x;
  int l15 = lane & 15, lg = lane >> 4;

  __shared__ __align__(16) char As[4 * 2048];   // ring: [buf][row 0..15][128B ^ ((row&7)<<4)]
  __shared__ __align__(16) char Bs[4 * 4096];   // ring: [buf][n 0..63][64B ^ ((n&3)<<4)]
  __shared__ __align__(16) unsigned short vt[16][72];

  const char* xb = (const char*)x;
  const char* wb = (const char*)wiT;

  // Pre-swizzled per-lane global sources (dest is linear: lane i -> base + i*16).
  // A DMA j: row = j*8 + (lane>>3), phys col (lane&7)*16, logical col ^= ((row&7)<<4).
  const char* pA0 = xb + (size_t)(m0 + (lane >> 3)) * 4096 + ((((lane & 7) ^ (lane >> 3))) << 4);
  const char* pA1 = pA0 + 8 * 4096;
  // B DMA j: n = j*16 + (lane>>2), phys col (lane&3)*16, logical col ^= ((n&3)<<4).
  const char* pB = wb + (size_t)(lane >> 2) * 2048 + ((((lane & 3) ^ ((lane >> 2) & 3))) << 4);

  auto ISSUE = [&](int st) {
    int buf = st & 3;
    char* ad = As + buf * 2048;
    char* bd = Bs + buf * 4096;
    GLOAD_LDS(pA0 + st * 128, ad);
    GLOAD_LDS(pA1 + st * 128, ad + 1024);
#pragma unroll
    for (int j = 0; j < 4; ++j) GLOAD_LDS(pB + j * 32768 + st * 64, bd + j * 1024);
  };

  f32x4 acc[4] = {};
  int swA = (l15 & 7) << 4;
  int swB = (l15 & 3) << 4;

  auto COMP = [&](int kt) {
    const char* Ab = As + (kt & 3) * 2048 + l15 * 128;
    f32x4 a0 = *(const f32x4*)(Ab + ((lg * 32) ^ swA));
    f32x4 a1 = *(const f32x4*)(Ab + ((lg * 32 + 16) ^ swA));
    bf16x8 af;
    af[0] = (__bf16)a0[0]; af[1] = (__bf16)a0[1]; af[2] = (__bf16)a0[2]; af[3] = (__bf16)a0[3];
    af[4] = (__bf16)a1[0]; af[5] = (__bf16)a1[1]; af[6] = (__bf16)a1[2]; af[7] = (__bf16)a1[3];
    const char* Bb = Bs + (kt & 3) * 4096 + ((lg * 16) ^ swB) + l15 * 64;
#pragma unroll
    for (int t = 0; t < 4; ++t) {
      bf16x8 bfr = *(const bf16x8*)(Bb + t * 1024);
      acc[t] = mfma16(af, bfr, acc[t]);
    }
  };

  ISSUE(0);
  ISSUE(1);
  ISSUE(2);
#pragma unroll 1
  for (int kt = 0; kt < 29; ++kt) {
    ISSUE(kt + 3);
    asm volatile("s_waitcnt vmcnt(18)" ::: "memory");  // stage kt landed; 3 in flight
    __builtin_amdgcn_sched_barrier(0);
    COMP(kt);
    __builtin_amdgcn_sched_barrier(0);  // keep next ISSUE below this COMP's ds_reads
  }
  asm volatile("s_waitcnt vmcnt(12)" ::: "memory");
  __builtin_amdgcn_sched_barrier(0);
  COMP(29);
  asm volatile("s_waitcnt vmcnt(6)" ::: "memory");
  __builtin_amdgcn_sched_barrier(0);
  COMP(30);
  asm volatile("s_waitcnt vmcnt(0)" ::: "memory");
  __builtin_amdgcn_sched_barrier(0);
  COMP(31);

  if (ten == 2) {
    // transpose 16 kv-rows x 64 d through tiny LDS, store vpT [b][dh][kv]
#pragma unroll
    for (int t = 0; t < 4; ++t)
#pragma unroll
      for (int r = 0; r < 4; ++r)
        vt[lg * 4 + r][t * 16 + l15] = f2bf(acc[t][r]);
    __syncthreads();  // single-wave block: cheap
    int bq = m0 >> 11, kvb = m0 & 2047;
    unsigned short* dst = vpT + (size_t)bq * (DHEAD * S_LEN) + (size_t)lane * S_LEN + kvb;
    ushort8 o0, o1;
#pragma unroll
    for (int j = 0; j < 8; ++j) {
      o0[j] = vt[j][lane];
      o1[j] = vt[8 + j][lane];
    }
    *(ushort8*)dst = o0;
    *(ushort8*)(dst + 8) = o1;
  } else {
#pragma unroll
    for (int t = 0; t < 4; ++t) {
      int gc = t * 16 + l15;
#pragma unroll
      for (int r = 0; r < 4; ++r) {
        size_t idx = (size_t)(m0 + lg * 4 + r) * DHEAD + gc;
        float val = acc[t][r];
        if (ten == 0) {
          qp32[idx] = val;
          qp_bf[idx] = f2bf(val * QK_SCALE);
        } else {
          kp_bf[idx] = f2bf(val);
        }
      }
    }
  }
}

// ---- flash attention, fixed-max softmax, 4-way KV split per block
// NO in-loop barriers: P_lds[w] is written AND read by wave w only -- the
// compiler's lgkmcnt dependency wait orders the round-trip. Waves fully
// decoupled until the final cross-wave combine barrier.
__global__ __launch_bounds__(256) void attn_kernel(
    const unsigned short* __restrict__ qp_bf, const unsigned short* __restrict__ kp_bf,
    const unsigned short* __restrict__ vpT, const float* __restrict__ qp32,
    unsigned short* __restrict__ head_bf) {
  int bx = blockIdx.x;
  int b = bx >> 7;
  int q0 = (bx & 127) << 4;
  int tid = threadIdx.x, lane = tid & 63, w = tid >> 6;
  int l15 = lane & 15, lg = lane >> 4;

  __shared__ __align__(16) unsigned short P_lds[4][16][72];  // per-wave P round-trip
  __shared__ __align__(16) float part[4][16][64];            // per-wave PV partials
  __shared__ float lsum_lds[4][16];                          // per-wave denom partials

  size_t base = (size_t)b * (S_LEN * DHEAD);
  const unsigned short* qrow_p = qp_bf + base + (size_t)(q0 + l15) * DHEAD + lg * 8;
  bf16x8 qf0 = *(const bf16x8*)qrow_p;  // B-frag: n=q, k=dh
  bf16x8 qf1 = *(const bf16x8*)(qrow_p + 32);

  const unsigned short* vbase = vpT + (size_t)b * (DHEAD * S_LEN);

  f32x4 oacc[4] = {};
  float lsum_p = 0.f;  // per-lane partial denom for q = q0 + l15

  for (int it = 0; it < 8; ++it) {
    int kv0 = w * 512 + it * 64;
    const unsigned short* kt = kp_bf + base + (size_t)kv0 * DHEAD;
    f32x4 sc[4];
    // swapped QK^T: mfma(K,Q) -> lane holds S(q = q0+l15, kv = kv0 + sub*16 + lg*4 + r)
#pragma unroll
    for (int sub = 0; sub < 4; ++sub) {
      bf16x8 kf0 = *(const bf16x8*)(kt + (size_t)(sub * 16 + l15) * DHEAD + lg * 8);
      bf16x8 kf1 = *(const bf16x8*)(kt + (size_t)(sub * 16 + l15) * DHEAD + 32 + lg * 8);
      f32x4 z = {};
      z = mfma16(kf0, qf0, z);
      sc[sub] = mfma16(kf1, qf1, z);
    }
    // fixed-max softmax: p = exp2(s); denom deferred (per-lane partial, q is lane-local)
#pragma unroll
    for (int sub = 0; sub < 4; ++sub) {
      ushort4v pw;
#pragma unroll
      for (int r = 0; r < 4; ++r) {
        float p = exp2f(sc[sub][r]);
        lsum_p += p;
        pw[r] = f2bf(p);
      }
      *(ushort4v*)&P_lds[w][l15][sub * 16 + lg * 4] = pw;  // row-local packed b64 write
    }
    // PV: A-frag = P (m=q, k=kv), B-frag = V^T (n=dh, k=kv), same k-order both sides
#pragma unroll
    for (int c = 0; c < 2; ++c) {
      bf16x8 pf = *(const bf16x8*)&P_lds[w][l15][c * 32 + lg * 8];  // same-wave read
      const unsigned short* vt2 = vbase + kv0 + c * 32 + lg * 8;
#pragma unroll
      for (int t = 0; t < 4; ++t) {
        bf16x8 vf = *(const bf16x8*)(vt2 + (size_t)(t * 16 + l15) * S_LEN);
        oacc[t] = mfma16(pf, vf, oacc[t]);
      }
    }
  }

  // finish denom: reduce across the 4 lg groups (same l15 = same q)
  lsum_p += __shfl_xor(lsum_p, 16);
  lsum_p += __shfl_xor(lsum_p, 32);

  // write per-wave partials (fixed-max => partials combine by plain addition)
#pragma unroll
  for (int t = 0; t < 4; ++t)
#pragma unroll
    for (int r = 0; r < 4; ++r)
      part[w][lg * 4 + r][t * 16 + l15] = oacc[t][r];
  if (lane < 16) lsum_lds[w][l15] = lsum_p;
  __syncthreads();  // cross-wave combine barrier (stays)

  {
    int qr = tid >> 4, d0 = (tid & 15) << 2;
    f32x4 s = *(const f32x4*)&part[0][qr][d0];
    s += *(const f32x4*)&part[1][qr][d0];
    s += *(const f32x4*)&part[2][qr][d0];
    s += *(const f32x4*)&part[3][qr][d0];
    float l = lsum_lds[0][qr] + lsum_lds[1][qr] + lsum_lds[2][qr] + lsum_lds[3][qr];
    float inv = 1.0f / l;
    size_t idx = base + (size_t)(q0 + qr) * DHEAD + d0;
    f32x4 qv = *(const f32x4*)(qp32 + idx);
    f32x4 res = qv + s * inv;
    ushort4v hb;
#pragma unroll
    for (int j = 0; j < 4; ++j) hb[j] = f2bf(res[j]);
    *(ushort4v*)(head_bf + idx) = hb;  // bf16 head: residual + normalized PV
  }
}

// ---- out = head_bf[8192x64] @ wosumT^T [64x1024] + bo, via MFMA (K=64)
// Same fragment conventions as proj (A rows = m, B rows = n, verified C-layout).
__global__ __launch_bounds__(256) void out_kernel(
    const unsigned short* __restrict__ head_bf, const unsigned short* __restrict__ wosumT,
    const float* __restrict__ bo, float* __restrict__ out) {
  int bx = blockIdx.x;
  int m0 = (bx >> 3) << 6;  // 128 row-blocks of 64
  int c0 = (bx & 7) << 7;   // 8 col-blocks of 128
  int tid = threadIdx.x, lane = tid & 63, w = tid >> 6;
  int l15 = lane & 15, lg = lane >> 4;

  const unsigned short* ap = head_bf + (size_t)(m0 + w * 16 + l15) * DHEAD + lg * 8;
  bf16x8 af0 = *(const bf16x8*)ap;         // k = lg*8..+8
  bf16x8 af1 = *(const bf16x8*)(ap + 32);  // k = 32+lg*8..+8

  f32x4 acc[8] = {};
#pragma unroll
  for (int t = 0; t < 8; ++t) {
    const unsigned short* bp = wosumT + (size_t)(c0 + t * 16 + l15) * DHEAD + lg * 8;
    bf16x8 b0 = *(const bf16x8*)bp;
    bf16x8 b1 = *(const bf16x8*)(bp + 32);
    acc[t] = mfma16(af0, b0, acc[t]);
    acc[t] = mfma16(af1, b1, acc[t]);
  }
#pragma unroll
  for (int t = 0; t < 8; ++t) {
    int col = c0 + t * 16 + l15;
    float bias = bo[col];
#pragma unroll
    for (int r = 0; r < 4; ++r) {
      int row = m0 + w * 16 + lg * 4 + r;
      out[(size_t)row * 1024 + col] = acc[t][r] + bias;
    }
  }
}

extern "C" void kernel_launch(void* const* d_in, const int* in_sizes, int n_in,
                              void* d_out, int out_size, void* d_ws, size_t ws_size,
                              hipStream_t stream) {
  (void)in_sizes; (void)n_in; (void)out_size; (void)ws_size;
  const float* v = (const float*)d_in[0];
  const float* k = (const float*)d_in[1];
  const float* q = (const float*)d_in[2];
  const float* wi = (const float*)d_in[3];
  const float* Wo = (const float*)d_in[4];
  const float* bo = (const float*)d_in[5];
  float* out = (float*)d_out;
  char* ws = (char*)d_ws;

  float* qp32 = (float*)(ws + 0);                                // 2 MB
  unsigned short* head_bf = (unsigned short*)(ws + (2u << 20));  // 1 MB
  unsigned short* qp_bf = (unsigned short*)(ws + (4u << 20));    // 1 MB
  unsigned short* kp_bf = (unsigned short*)(ws + (5u << 20));    // 1 MB
  unsigned short* vpT = (unsigned short*)(ws + (6u << 20));      // 1 MB  [b][dh][kv]
  unsigned short* wiT = (unsigned short*)(ws + (7u << 20));      // 128 KB
  unsigned short* wosumT = (unsigned short*)(ws + (7u << 20) + (512u << 10));  // 128 KB

  prep_kernel<<<512, 256, 0, stream>>>(wi, Wo, wiT, wosumT);
  proj_kernel<<<1536, 64, 0, stream>>>(q, k, v, wiT, qp32, qp_bf, kp_bf, vpT);
  attn_kernel<<<512, 256, 0, stream>>>(qp_bf, kp_bf, vpT, qp32, head_bf);
  out_kernel<<<1024, 256, 0, stream>>>(head_bf, wosumT, bo, out);
}